// Round 1
// baseline (137.236 us; speedup 1.0000x reference)
//
#include <hip/hip_runtime.h>

// Problem constants (from reference): B=8, M=512, A=16, F=128, fp32.
// out[b,m,d,f] = sum_{a,c} x[b,m,a,f] * y[b,m,c,f] * cgc[a,d,c]
// Factored as: out_d = sum_a x_a * ( sum_c cgc[a,d,c] * y_c ), per (b,m,f).
//
// Thread layout: one thread handles one (b*M+m, f0..f0+3) strip of 4 f's.
//   - y strip (16 c x float4) register-resident, statically indexed (c unrolled)
//   - acc (16 d x float4) register-resident, statically indexed (d unrolled)
//   - a-loop dynamic (#pragma unroll 1) to keep code ~9KB (I$ = 32KB)
//   - cgc rows cgc[a][d][0..15] are contiguous 64B, wave-uniform -> SMEM s_load

#define AA 16
#define FF 128

__global__ __launch_bounds__(256, 2)
void tpc_fp32_kernel(const float* __restrict__ x,
                     const float* __restrict__ y,
                     const float* __restrict__ cgc,
                     float* __restrict__ out) {
    const int tid = blockIdx.x * 256 + threadIdx.x;
    const int f0  = (tid & 31) << 2;   // f offset: 0,4,...,124
    const int bm  = tid >> 5;          // 0..4095

    const size_t base = ((size_t)bm * AA) * FF + f0;
    const float* xp = x + base;
    const float* yp = y + base;
    float*       op = out + base;

    // y strip into registers: yr[c] = y[bm, c, f0..f0+3]
    float4 yr[AA];
#pragma unroll
    for (int c = 0; c < AA; ++c)
        yr[c] = *(const float4*)(yp + (size_t)c * FF);

    float4 acc[AA];
#pragma unroll
    for (int d = 0; d < AA; ++d)
        acc[d] = make_float4(0.f, 0.f, 0.f, 0.f);

#pragma unroll 1
    for (int a = 0; a < AA; ++a) {
        const float4 xa = *(const float4*)(xp + (size_t)a * FF);
        const float* cg = cgc + (size_t)a * AA * AA;   // cg[d*16 + c], rows contiguous in c
#pragma unroll
        for (int d = 0; d < AA; ++d) {
            float sx = 0.f, sy = 0.f, sz = 0.f, sw = 0.f;
#pragma unroll
            for (int c = 0; c < AA; ++c) {
                const float w = cg[d * AA + c];   // wave-uniform -> scalar load
                sx += w * yr[c].x;
                sy += w * yr[c].y;
                sz += w * yr[c].z;
                sw += w * yr[c].w;
            }
            acc[d].x += xa.x * sx;
            acc[d].y += xa.y * sy;
            acc[d].z += xa.z * sz;
            acc[d].w += xa.w * sw;
        }
    }

#pragma unroll
    for (int d = 0; d < AA; ++d)
        *(float4*)(op + (size_t)d * FF) = acc[d];
}

extern "C" void kernel_launch(void* const* d_in, const int* in_sizes, int n_in,
                              void* d_out, int out_size, void* d_ws, size_t ws_size,
                              hipStream_t stream) {
    const float* x   = (const float*)d_in[0];
    const float* y   = (const float*)d_in[1];
    const float* cgc = (const float*)d_in[2];
    float* out = (float*)d_out;

    // threads = out_size / (16 d * 4 f per thread) = 131072 -> 512 blocks x 256
    const int threads = out_size / (AA * 4);
    const int block = 256;
    const int grid = threads / block;

    hipLaunchKernelGGL(tpc_fp32_kernel, dim3(grid), dim3(block), 0, stream,
                       x, y, cgc, out);
}

// Round 2
// 133.646 us; speedup vs baseline: 1.0269x; 1.0269x over previous
//
#include <hip/hip_runtime.h>

// out[b,m,d,f] = sum_{a,c} x[b,m,a,f] * y[b,m,c,f] * cgc[a,d,c]
// Factored: out_d = sum_a x_a * (sum_c cgc[a,d,c] * y_c), per (b,m,f).
//
// Round 2 changes vs round 1 (latency-bound, VALUBusy 38%, 2 waves/SIMD):
//  - f strip of 2 (not 4): 262144 threads = 4096 waves = 4/SIMD. VGPR ~80.
//  - all FMAs as float2 vectors -> v_pk_fma_f32 (halves VALU issue: 29->14.5us floor)
//  - software-pipelined prefetch of next x row across the dynamic a-loop
//  - cgc rows remain wave-uniform -> scalar s_load path, d-loop unrolled so the
//    scheduler can keep a few 16-float rows in flight within the SGPR budget.

typedef float v2f __attribute__((ext_vector_type(2)));

#define AA 16
#define FF 128

__global__ __launch_bounds__(256, 4)
void tpc_pk_kernel(const float* __restrict__ x,
                   const float* __restrict__ y,
                   const float* __restrict__ cgc,
                   float* __restrict__ out) {
    const int tid = blockIdx.x * 256 + threadIdx.x;
    const int f0  = (tid & 63) << 1;   // f offset: 0,2,...,126 (wave covers 512B contiguous)
    const int bm  = tid >> 6;          // 0..4095

    const size_t base = ((size_t)bm * AA) * FF + f0;
    const float* xp = x + base;
    const float* yp = y + base;
    float*       op = out + base;

    // y strip register-resident: yr[c] = y[bm, c, f0..f0+1]
    v2f yr[AA];
#pragma unroll
    for (int c = 0; c < AA; ++c)
        yr[c] = *(const v2f*)(yp + (size_t)c * FF);

    v2f acc[AA];
#pragma unroll
    for (int d = 0; d < AA; ++d)
        acc[d] = (v2f){0.f, 0.f};

    // software pipeline: xa holds row a, xn prefetches row a+1
    v2f xa = *(const v2f*)xp;
#pragma unroll 1
    for (int a = 0; a < AA; ++a) {
        const int an = (a + 1) & (AA - 1);          // row 15 re-reads row 0 (cached, branch-free)
        const v2f xn = *(const v2f*)(xp + (size_t)an * FF);
        const float* cg = cgc + (size_t)a * AA * AA; // wave-uniform -> s_load rows
#pragma unroll
        for (int d = 0; d < AA; ++d) {
            v2f s = (v2f){0.f, 0.f};
#pragma unroll
            for (int c = 0; c < AA; ++c) {
                const float w = cg[d * AA + c];
                const v2f wv = {w, w};
                s = __builtin_elementwise_fma(wv, yr[c], s);   // v_pk_fma_f32
            }
            acc[d] = __builtin_elementwise_fma(xa, s, acc[d]); // v_pk_fma_f32
        }
        xa = xn;
    }

#pragma unroll
    for (int d = 0; d < AA; ++d)
        *(v2f*)(op + (size_t)d * FF) = acc[d];
}

extern "C" void kernel_launch(void* const* d_in, const int* in_sizes, int n_in,
                              void* d_out, int out_size, void* d_ws, size_t ws_size,
                              hipStream_t stream) {
    const float* x   = (const float*)d_in[0];
    const float* y   = (const float*)d_in[1];
    const float* cgc = (const float*)d_in[2];
    float* out = (float*)d_out;

    // threads = out_size / (16 d * 2 f per thread) = 262144 -> 1024 blocks x 256
    const int threads = out_size / (AA * 2);
    const int block = 256;
    const int grid = threads / block;

    hipLaunchKernelGGL(tpc_pk_kernel, dim3(grid), dim3(block), 0, stream,
                       x, y, cgc, out);
}

// Round 3
// 114.980 us; speedup vs baseline: 1.1936x; 1.1623x over previous
//
#include <hip/hip_runtime.h>
#include <hip/hip_bf16.h>

// out[b,m,d,f] = sum_{a,c} x[b,m,a,f] * y[b,m,c,f] * cgc[a,d,c]
// MFMA formulation, per bm point: out[16,128] = W[16,256] . P[256,128]
//   k = a*16 + c;  W[d,k] = cgc[a,d,c]  (wave-uniform, register-resident)
//   P[k,f] = x[a,f] * y[c,f]            (built on the fly in bf16)
// mfma_f32_16x16x32_bf16: m=d(16), n=f-tile(16), K=(a,c); 8 f-tiles x 8 K-steps.
//
// Fragment layout (CDNA standard): L=lane&15, quad=lane>>4
//   A[m=L][k=quad*8+j]   B[k=quad*8+j][n=L]   D[row=quad*4+r][col=L]
// k_global = 32t + quad*8 + j  ->  a = 2t + (quad>>1),  c = (quad&1)*8 + j
//   => W-frag for step t: cgc[(2t+qh)*256 + L*16 + c0 + (0..7)]  (contiguous!)
//   => B-frag: x[2t+qh, f] * y[c0+j, f]  -- 8 x + 8 y scalars per lane per tile
// One wave per bm; 4096 waves = 1024 blocks x 256; no LDS, no barriers.

typedef __attribute__((ext_vector_type(8))) short  short8;
typedef __attribute__((ext_vector_type(4))) float  floatx4;
typedef __attribute__((ext_vector_type(4))) unsigned int uintx4;

#define AA 16
#define FF 128

static __device__ __forceinline__ unsigned int pack_bf16_2(float lo, float hi) {
    __hip_bfloat162 h = __float22bfloat162_rn(make_float2(lo, hi));  // v_cvt_pk_bf16_f32
    unsigned int u;
    __builtin_memcpy(&u, &h, 4);
    return u;
}

__global__ __launch_bounds__(256, 4)
void tpc_mfma_kernel(const float* __restrict__ x,
                     const float* __restrict__ y,
                     const float* __restrict__ cgc,
                     float* __restrict__ out) {
    const int wave = threadIdx.x >> 6;
    const int lane = threadIdx.x & 63;
    const int L    = lane & 15;       // A: m(=d); B: n(=f within tile); D: col
    const int quad = lane >> 4;
    const int qh   = quad >> 1;       // a parity
    const int c0   = (quad & 1) * 8;  // c sub-range

    const int bm = blockIdx.x * 4 + wave;   // 0..4095

    // ---- A fragments (W), register-resident: 8 steps x 8 bf16 ----
    short8 wfrag[8];
#pragma unroll
    for (int t = 0; t < 8; ++t) {
        const float* wp = cgc + (2 * t + qh) * (AA * AA) + L * AA + c0;
        const floatx4 w0 = *(const floatx4*)(wp);
        const floatx4 w1 = *(const floatx4*)(wp + 4);
        uintx4 u;
        u.x = pack_bf16_2(w0.x, w0.y);
        u.y = pack_bf16_2(w0.z, w0.w);
        u.z = pack_bf16_2(w1.x, w1.y);
        u.w = pack_bf16_2(w1.z, w1.w);
        wfrag[t] = __builtin_bit_cast(short8, u);
    }

    const float* xb = x   + (size_t)bm * (AA * FF);
    const float* yb = y   + (size_t)bm * (AA * FF);
    float*       ob = out + (size_t)bm * (AA * FF);

#pragma unroll 1
    for (int tile = 0; tile < 8; ++tile) {
        const int f = tile * 16 + L;

        float yv[8], xv[8];
#pragma unroll
        for (int j = 0; j < 8; ++j) yv[j] = yb[(c0 + j) * FF + f];
#pragma unroll
        for (int t = 0; t < 8; ++t) xv[t] = xb[(2 * t + qh) * FF + f];

        floatx4 acc = {0.f, 0.f, 0.f, 0.f};
#pragma unroll
        for (int t = 0; t < 8; ++t) {
            const float xs = xv[t];
            uintx4 u;
            u.x = pack_bf16_2(xs * yv[0], xs * yv[1]);
            u.y = pack_bf16_2(xs * yv[2], xs * yv[3]);
            u.z = pack_bf16_2(xs * yv[4], xs * yv[5]);
            u.w = pack_bf16_2(xs * yv[6], xs * yv[7]);
            const short8 bfrag = __builtin_bit_cast(short8, u);
            acc = __builtin_amdgcn_mfma_f32_16x16x32_bf16(wfrag[t], bfrag, acc, 0, 0, 0);
        }

#pragma unroll
        for (int r = 0; r < 4; ++r)
            ob[(quad * 4 + r) * FF + f] = acc[r];
    }
}

extern "C" void kernel_launch(void* const* d_in, const int* in_sizes, int n_in,
                              void* d_out, int out_size, void* d_ws, size_t ws_size,
                              hipStream_t stream) {
    const float* x   = (const float*)d_in[0];
    const float* y   = (const float*)d_in[1];
    const float* cgc = (const float*)d_in[2];
    float* out = (float*)d_out;

    // 4096 bm points, one wave each -> 1024 blocks x 256 threads (4 waves/block)
    hipLaunchKernelGGL(tpc_mfma_kernel, dim3(1024), dim3(256), 0, stream,
                       x, y, cgc, out);
}